// Round 10
// baseline (314.024 us; speedup 1.0000x reference)
//
#include <hip/hip_runtime.h>
#include <math.h>

#define NB 50000
#define NE 600000
#define NG 2000
#define ND 64
#define HID 128
#define BN_EPS 1e-5f
#define NBLK 196          // ceil(NB/256)
#define MPAD 50176        // padded rows for GEMM tiles
#define GATHER_BLKS 3125  // NB*16/256 exactly
#define RED_L1_BLKS 125   // 3125/25
#define EBLK 2344         // ceil(NE/256)

typedef __attribute__((ext_vector_type(8))) short bf16x8;
typedef __attribute__((ext_vector_type(4))) float f32x4;
typedef unsigned int uint;
typedef unsigned short ushort;

__device__ __forceinline__ ushort f2b(float f) {
  uint u = __builtin_bit_cast(uint, f);
  u = u + 0x7fffu + ((u >> 16) & 1u);  // RNE
  return (ushort)(u >> 16);
}
__device__ __forceinline__ float blo(uint u) {
  return __builtin_bit_cast(float, u << 16);
}
__device__ __forceinline__ float bhi(uint u) {
  return __builtin_bit_cast(float, u & 0xffff0000u);
}

// ---- pass 1: rank[e] = arrival index within dst bucket; cnt = in-degree ----
__global__ __launch_bounds__(256) void rank_kernel(const int* __restrict__ dst,
                                                   int* __restrict__ cnt,
                                                   int* __restrict__ rank) {
  int e = blockIdx.x * 256 + threadIdx.x;
  if (e < NE) rank[e] = atomicAdd(&cnt[dst[e]], 1);
}

// ---- prefix scan over cnt (multi-block) + dis fold -------------------------
__global__ __launch_bounds__(256) void scan1(const int* __restrict__ cnt,
                                             int* __restrict__ part,
                                             int* __restrict__ bsum,
                                             float* __restrict__ dis) {
  __shared__ int tmp[256];
  int tid = threadIdx.x;
  int i = blockIdx.x * 256 + tid;
  int v = (i < NB) ? cnt[i] : 0;
  if (i < NB) dis[i] = rsqrtf((float)(v + 1));  // +1 self-loop
  tmp[tid] = v;
  __syncthreads();
  for (int off = 1; off < 256; off <<= 1) {
    int t = (tid >= off) ? tmp[tid - off] : 0;
    __syncthreads();
    tmp[tid] += t;
    __syncthreads();
  }
  if (i < NB) part[i] = tmp[tid] - v;
  if (tid == 255) bsum[blockIdx.x] = tmp[255];
}

__global__ __launch_bounds__(256) void scan2(int* __restrict__ bsum,
                                             int* __restrict__ boffs) {
  __shared__ int tmp[256];
  int tid = threadIdx.x;
  int v = (tid < NBLK) ? bsum[tid] : 0;
  tmp[tid] = v;
  __syncthreads();
  for (int off = 1; off < 256; off <<= 1) {
    int t = (tid >= off) ? tmp[tid - off] : 0;
    __syncthreads();
    tmp[tid] += t;
    __syncthreads();
  }
  if (tid < NBLK) boffs[tid] = tmp[tid] - v;
}

__global__ __launch_bounds__(256) void scan3(int* __restrict__ part,
                                             const int* __restrict__ boffs) {
  int i = blockIdx.x * 256 + threadIdx.x;
  if (i < NB) part[i] += boffs[blockIdx.x];
  if (i == 0) part[NB] = NE;
}

// ---- pass 2: atomic-free CSR fill (4B payload) + graph_bounds tail ---------
__global__ __launch_bounds__(256) void fill2(const int* __restrict__ src,
                                             const int* __restrict__ dst,
                                             const int* __restrict__ rank,
                                             const int* __restrict__ row_ptr,
                                             int* __restrict__ e_src,
                                             const int* __restrict__ batch,
                                             int* __restrict__ g_start) {
  int bid = blockIdx.x;
  int tid = threadIdx.x;
  if (bid < EBLK) {
    int e = bid * 256 + tid;
    if (e >= NE) return;
    int s = src[e], d = dst[e];
    e_src[row_ptr[d] + rank[e]] = s;
  } else {
    int g = (bid - EBLK) * 256 + tid;
    if (g > NG) return;
    if (g == NG) { g_start[NG] = NB; return; }
    int lo = 0, hi = NB;
    while (lo < hi) {
      int mid = (lo + hi) >> 1;
      if (batch[mid] < g) lo = mid + 1; else hi = mid;
    }
    g_start[g] = lo;
  }
}

// ---- weight packing helper -------------------------------------------------
// Bp layout: ((nf*nkf+kf)*64+lane)*8+j -> W[kf*32+(lane>>4)*8+j][nf*16+(lane&15)]
__device__ __forceinline__ void pack_slice(const float* __restrict__ W, int K,
                                           const float* __restrict__ a_s,
                                           ushort* __restrict__ Bp, int slice,
                                           int tid) {
  int nkf = K >> 5;
  int i = slice * 1024 + tid;
  int total = nkf * 4096;
#pragma unroll 4
  for (int u = 0; u < 4; u++, i += 256) {
    if (i < total) {
      int j = i & 7;
      int lane = (i >> 3) & 63;
      int rem = i >> 9;
      int kf = rem % nkf;
      int nf = rem / nkf;
      int k = kf * 32 + (lane >> 4) * 8 + j;
      int col = nf * 16 + (lane & 15);
      float a = a_s ? a_s[k] : 1.f;
      Bp[i] = f2b(a * W[k * 128 + col]);
    }
  }
}

// ---- initial packing: lin (K=64, blocks 0-7) + conv0 (blocks 8-23) ---------
__global__ __launch_bounds__(256) void pack_init(const float* __restrict__ lin_w,
                                                 const float* __restrict__ lin_b,
                                                 const float* __restrict__ conv_w0,
                                                 ushort* __restrict__ Bp0,
                                                 ushort* __restrict__ Bp1,
                                                 float* __restrict__ bias0,
                                                 float* __restrict__ bias1) {
  int bid = blockIdx.x, tid = threadIdx.x;
  if (bid == 0 && tid < 128) {
    bias0[tid] = lin_b[tid];
    bias1[tid] = 0.f;
  }
  if (bid < 8)
    pack_slice(lin_w, 64, nullptr, Bp0, bid, tid);
  else
    pack_slice(conv_w0, 128, nullptr, Bp1, bid - 8, tid);
}

// ---- stats level-1 reduce: [3125][256] -> [125][256] -----------------------
__global__ __launch_bounds__(256) void reduce_l1(const float* __restrict__ partial,
                                                 float* __restrict__ partial2) {
  int tid = threadIdx.x;
  int b = blockIdx.x;
  float s = 0.f;
#pragma unroll 5
  for (int r = b * 25; r < b * 25 + 25; r++)
    s += partial[(size_t)r * 256 + tid];
  partial2[(size_t)b * 256 + tid] = s;
}

// ---- fused finalize (125-row reduce, L2-hot) + BN fold + pack (16 blocks) --
__global__ __launch_bounds__(256) void pack_final(
    const float* __restrict__ W, const float* __restrict__ partial2,
    const float* __restrict__ gamma, const float* __restrict__ beta,
    const float* __restrict__ bias_in, ushort* __restrict__ Bp,
    float* __restrict__ bias_out) {
  __shared__ float a_s[128], b_s[128];
  __shared__ float red[256];
  int t = threadIdx.x;
  float s = 0.f;
#pragma unroll 5
  for (int r = 0; r < RED_L1_BLKS; r++) s += partial2[(size_t)r * 256 + t];
  red[t] = s;
  __syncthreads();
  if (t < 128) {
    float mu = red[t] * (1.f / NB);
    float var = red[128 + t] * (1.f / NB) - mu * mu;
    float a = gamma[t] * rsqrtf(var + BN_EPS);
    a_s[t] = a;
    b_s[t] = beta[t] - mu * a;
  }
  __syncthreads();
  if (blockIdx.x == 0 && t < 128) {
    float acc = bias_in ? bias_in[t] : 0.f;
    for (int k = 0; k < 128; k++) acc += b_s[k] * W[k * 128 + t];
    bias_out[t] = acc;
  }
  pack_slice(W, 128, a_s, Bp, blockIdx.x, t);
}

// ---- bf16 MFMA GEMM: C[M,128] = A[M,K] @ Bp (+bias, opt relu) --------------
// DSCALE: multiply output row by dscale[row] (pre-scales h for gather).
template <bool RELU, bool F32A, bool DSCALE>
__global__ __launch_bounds__(256) void gemm_mfma(const void* __restrict__ Av,
                                                 const ushort* __restrict__ Bp,
                                                 const float* __restrict__ bias,
                                                 const float* __restrict__ dscale,
                                                 ushort* __restrict__ C, int M,
                                                 int K) {
  __shared__ ushort Blds[16384];
  const int tid = threadIdx.x;
  const int lane = tid & 63;
  const int w = tid >> 6;
  const int nkf = K >> 5;
  for (int i = tid; i < nkf * 512; i += 256)
    reinterpret_cast<uint4*>(Blds)[i] = reinterpret_cast<const uint4*>(Bp)[i];
  __syncthreads();

  const int rbase = blockIdx.x * 128 + w * 32;
  f32x4 acc[2][8];
#pragma unroll
  for (int m = 0; m < 2; m++)
#pragma unroll
    for (int n = 0; n < 8; n++) acc[m][n] = (f32x4){0.f, 0.f, 0.f, 0.f};

  const int arow0 = rbase + (lane & 15);
  const int arow1 = arow0 + 16;
  const int ra0 = F32A ? (arow0 < M ? arow0 : M - 1) : arow0;
  const int ra1 = F32A ? (arow1 < M ? arow1 : M - 1) : arow1;
  const int acol = (lane >> 4) * 8;
#pragma unroll 4
  for (int kf = 0; kf < nkf; kf++) {
    bf16x8 a0, a1;
    if constexpr (F32A) {
      const float* Af = (const float*)Av;
      const float4* p0 =
          reinterpret_cast<const float4*>(Af + (size_t)ra0 * K + kf * 32 + acol);
      const float4* p1 =
          reinterpret_cast<const float4*>(Af + (size_t)ra1 * K + kf * 32 + acol);
      float4 u0 = p0[0], u1 = p0[1], v0 = p1[0], v1 = p1[1];
      a0[0] = (short)f2b(u0.x); a0[1] = (short)f2b(u0.y);
      a0[2] = (short)f2b(u0.z); a0[3] = (short)f2b(u0.w);
      a0[4] = (short)f2b(u1.x); a0[5] = (short)f2b(u1.y);
      a0[6] = (short)f2b(u1.z); a0[7] = (short)f2b(u1.w);
      a1[0] = (short)f2b(v0.x); a1[1] = (short)f2b(v0.y);
      a1[2] = (short)f2b(v0.z); a1[3] = (short)f2b(v0.w);
      a1[4] = (short)f2b(v1.x); a1[5] = (short)f2b(v1.y);
      a1[6] = (short)f2b(v1.z); a1[7] = (short)f2b(v1.w);
    } else {
      const ushort* A = (const ushort*)Av;
      a0 = *reinterpret_cast<const bf16x8*>(A + (size_t)ra0 * K + kf * 32 + acol);
      a1 = *reinterpret_cast<const bf16x8*>(A + (size_t)ra1 * K + kf * 32 + acol);
    }
#pragma unroll
    for (int nf = 0; nf < 8; nf++) {
      bf16x8 b = *reinterpret_cast<const bf16x8*>(
          &Blds[((nf * nkf + kf) * 64 + lane) * 8]);
      acc[0][nf] = __builtin_amdgcn_mfma_f32_16x16x32_bf16(a0, b, acc[0][nf], 0, 0, 0);
      acc[1][nf] = __builtin_amdgcn_mfma_f32_16x16x32_bf16(a1, b, acc[1][nf], 0, 0, 0);
    }
  }

#pragma unroll
  for (int m = 0; m < 2; m++) {
    int row0 = rbase + m * 16 + (lane >> 4) * 4;
#pragma unroll
    for (int nf = 0; nf < 8; nf++) {
      int col = nf * 16 + (lane & 15);
      float bv = bias[col];
#pragma unroll
      for (int r = 0; r < 4; r++) {
        int row = row0 + r;
        if (row < M) {
          float v = acc[m][nf][r] + bv;
          if (RELU) v = fmaxf(v, 0.f);
          if (DSCALE) v *= dscale[row];
          C[(size_t)row * 128 + col] = f2b(v);
        }
      }
    }
  }
}

// ---- conv aggregation: gather of pre-scaled h' (pure adds, 4 indep chains) -
// y[v] = relu(bias + dis[v] * (h'[v] + sum_e h'[e_src]))
__global__ __launch_bounds__(256) void gather_conv(
    const ushort* __restrict__ h, const int* __restrict__ e_src,
    const int* __restrict__ row_ptr, const float* __restrict__ dis,
    const float* __restrict__ bias, ushort* __restrict__ y,
    float* __restrict__ partial) {
  __shared__ float red[2048];
  int tid = threadIdx.x;
  int gid = blockIdx.x * 256 + tid;
  int v = gid >> 4;  // grid == NB*16 exactly
  int c8 = gid & 15;
  const uint4* h4 = reinterpret_cast<const uint4*>(h);
  float sv = dis[v];
  uint4 hv = h4[(size_t)v * 16 + c8];
  float a1[8], a2[8], a3[8], a4[8];
  a1[0] = blo(hv.x); a1[1] = bhi(hv.x);
  a1[2] = blo(hv.y); a1[3] = bhi(hv.y);
  a1[4] = blo(hv.z); a1[5] = bhi(hv.z);
  a1[6] = blo(hv.w); a1[7] = bhi(hv.w);
#pragma unroll
  for (int j = 0; j < 8; j++) { a2[j] = 0.f; a3[j] = 0.f; a4[j] = 0.f; }
  int beg = row_ptr[v], end = row_ptr[v + 1];
  int e = beg;
  for (; e + 4 <= end; e += 4) {
    int s0 = e_src[e], s1 = e_src[e + 1], s2 = e_src[e + 2], s3 = e_src[e + 3];
    uint4 q0 = h4[(size_t)s0 * 16 + c8];
    uint4 q1 = h4[(size_t)s1 * 16 + c8];
    uint4 q2 = h4[(size_t)s2 * 16 + c8];
    uint4 q3 = h4[(size_t)s3 * 16 + c8];
    a1[0] += blo(q0.x); a2[0] += blo(q1.x); a3[0] += blo(q2.x); a4[0] += blo(q3.x);
    a1[1] += bhi(q0.x); a2[1] += bhi(q1.x); a3[1] += bhi(q2.x); a4[1] += bhi(q3.x);
    a1[2] += blo(q0.y); a2[2] += blo(q1.y); a3[2] += blo(q2.y); a4[2] += blo(q3.y);
    a1[3] += bhi(q0.y); a2[3] += bhi(q1.y); a3[3] += bhi(q2.y); a4[3] += bhi(q3.y);
    a1[4] += blo(q0.z); a2[4] += blo(q1.z); a3[4] += blo(q2.z); a4[4] += blo(q3.z);
    a1[5] += bhi(q0.z); a2[5] += bhi(q1.z); a3[5] += bhi(q2.z); a4[5] += bhi(q3.z);
    a1[6] += blo(q0.w); a2[6] += blo(q1.w); a3[6] += blo(q2.w); a4[6] += blo(q3.w);
    a1[7] += bhi(q0.w); a2[7] += bhi(q1.w); a3[7] += bhi(q2.w); a4[7] += bhi(q3.w);
  }
  for (; e < end; ++e) {
    int s0 = e_src[e];
    uint4 q0 = h4[(size_t)s0 * 16 + c8];
    a1[0] += blo(q0.x); a1[1] += bhi(q0.x);
    a1[2] += blo(q0.y); a1[3] += bhi(q0.y);
    a1[4] += blo(q0.z); a1[5] += bhi(q0.z);
    a1[6] += blo(q0.w); a1[7] += bhi(q0.w);
  }
  float acc[8];
#pragma unroll
  for (int j = 0; j < 8; j++)
    acc[j] = fmaxf(bias[c8 * 8 + j] + sv * ((a1[j] + a2[j]) + (a3[j] + a4[j])),
                   0.f);
  uint4 o;
  o.x = (uint)f2b(acc[0]) | ((uint)f2b(acc[1]) << 16);
  o.y = (uint)f2b(acc[2]) | ((uint)f2b(acc[3]) << 16);
  o.z = (uint)f2b(acc[4]) | ((uint)f2b(acc[5]) << 16);
  o.w = (uint)f2b(acc[6]) | ((uint)f2b(acc[7]) << 16);
  reinterpret_cast<uint4*>(y)[(size_t)v * 16 + c8] = o;

  // fused per-block stats partials (no atomics)
#pragma unroll
  for (int j = 0; j < 8; j++) red[tid * 8 + j] = acc[j];
  __syncthreads();
  for (int st = 128; st >= 16; st >>= 1) {
    if (tid < st)
#pragma unroll
      for (int j = 0; j < 8; j++) red[tid * 8 + j] += red[(tid + st) * 8 + j];
    __syncthreads();
  }
  if (tid < 16)
#pragma unroll
    for (int j = 0; j < 8; j++)
      partial[(size_t)blockIdx.x * 256 + tid * 8 + j] = red[tid * 8 + j];
  __syncthreads();
#pragma unroll
  for (int j = 0; j < 8; j++) red[tid * 8 + j] = acc[j] * acc[j];
  __syncthreads();
  for (int st = 128; st >= 16; st >>= 1) {
    if (tid < st)
#pragma unroll
      for (int j = 0; j < 8; j++) red[tid * 8 + j] += red[(tid + st) * 8 + j];
    __syncthreads();
  }
  if (tid < 16)
#pragma unroll
    for (int j = 0; j < 8; j++)
      partial[(size_t)blockIdx.x * 256 + 128 + tid * 8 + j] = red[tid * 8 + j];
}

// ---- pooling: vectorized segmented gather (16 lanes/graph, uint4) ----------
__global__ __launch_bounds__(256) void pool_gather(const ushort* __restrict__ emb,
                                                   const int* __restrict__ g_start,
                                                   float* __restrict__ g) {
  int gid = blockIdx.x * 256 + threadIdx.x;
  int gr = gid >> 4;
  if (gr >= NG) return;
  int c8 = gid & 15;
  const uint4* e4 = reinterpret_cast<const uint4*>(emb);
  float acc[8];
#pragma unroll
  for (int j = 0; j < 8; j++) acc[j] = 0.f;
  int beg = g_start[gr], end = g_start[gr + 1];
  for (int v = beg; v < end; ++v) {
    uint4 q = e4[(size_t)v * 16 + c8];
    acc[0] += blo(q.x); acc[1] += bhi(q.x);
    acc[2] += blo(q.y); acc[3] += bhi(q.y);
    acc[4] += blo(q.z); acc[5] += bhi(q.z);
    acc[6] += blo(q.w); acc[7] += bhi(q.w);
  }
  float4* gp = reinterpret_cast<float4*>(g + (size_t)gr * 128 + c8 * 8);
  gp[0] = make_float4(acc[0], acc[1], acc[2], acc[3]);
  gp[1] = make_float4(acc[4], acc[5], acc[6], acc[7]);
}

// ---- head: 128->64->32->2 MLP, 4 graphs/block (500 blocks), LDS weights ----
__global__ __launch_bounds__(128) void head_kernel(
    const float* __restrict__ g, const float* __restrict__ w1,
    const float* __restrict__ b1, const float* __restrict__ w2,
    const float* __restrict__ b2, const float* __restrict__ wp,
    const float* __restrict__ bp, float* __restrict__ out) {
  __shared__ float w1s[128 * 64];
  __shared__ float w2s[64 * 32];
  __shared__ float wps[64];
  __shared__ float sg[128], ph[128], sh1[64], sh2[32];
  int tid = threadIdx.x;
  for (int i = tid; i < 2048; i += 128)
    reinterpret_cast<float4*>(w1s)[i] = reinterpret_cast<const float4*>(w1)[i];
  for (int i = tid; i < 512; i += 128)
    reinterpret_cast<float4*>(w2s)[i] = reinterpret_cast<const float4*>(w2)[i];
  if (tid < 64) wps[tid] = wp[tid];
  __syncthreads();

  for (int gi = 0; gi < 4; gi++) {
    int gid = blockIdx.x * 4 + gi;
    if (gid >= NG) break;
    sg[tid] = g[(size_t)gid * 128 + tid];
    __syncthreads();
    {
      int o = tid & 63, h = tid >> 6;
      float acc = 0.f;
#pragma unroll 8
      for (int k = 0; k < 64; k++)
        acc += sg[h * 64 + k] * w1s[(h * 64 + k) * 64 + o];
      ph[tid] = acc;
    }
    __syncthreads();
    if (tid < 64) sh1[tid] = fmaxf(b1[tid] + ph[tid] + ph[tid + 64], 0.f);
    __syncthreads();
    {
      int o = tid & 31, q = tid >> 5;
      float acc = 0.f;
#pragma unroll 8
      for (int k = 0; k < 16; k++)
        acc += sh1[q * 16 + k] * w2s[(q * 16 + k) * 32 + o];
      ph[tid] = acc;
    }
    __syncthreads();
    if (tid < 32)
      sh2[tid] = fmaxf(
          b2[tid] + ph[tid] + ph[tid + 32] + ph[tid + 64] + ph[tid + 96], 0.f);
    __syncthreads();
    if (tid < 2) {
      float acc = bp[tid];
#pragma unroll
      for (int k = 0; k < 32; k++) acc += sh2[k] * wps[k * 2 + tid];
      out[(size_t)gid * 2 + tid] = acc;
    }
    __syncthreads();
  }
}

extern "C" void kernel_launch(void* const* d_in, const int* in_sizes, int n_in,
                              void* d_out, int out_size, void* d_ws,
                              size_t ws_size, hipStream_t stream) {
  const float* x = (const float*)d_in[0];
  const int* ei = (const int*)d_in[1];
  const int* batch = (const int*)d_in[2];
  const float* lin_w = (const float*)d_in[3];
  const float* lin_b = (const float*)d_in[4];
  const float* conv_w = (const float*)d_in[5];
  const float* conv_b = (const float*)d_in[6];
  const float* bn_g = (const float*)d_in[7];
  const float* bn_b = (const float*)d_in[8];
  const float* emb_w = (const float*)d_in[9];
  const float* emb_b = (const float*)d_in[10];
  const float* m1w = (const float*)d_in[11];
  const float* m1b = (const float*)d_in[12];
  const float* m2w = (const float*)d_in[13];
  const float* m2b = (const float*)d_in[14];
  const float* pw = (const float*)d_in[15];
  const float* pb = (const float*)d_in[16];
  float* out = (float*)d_out;

  ushort* buf0 = (ushort*)d_ws;                  // [MPAD,128] bf16
  ushort* buf1 = buf0 + (size_t)MPAD * 128;      // [MPAD,128] bf16
  ushort* Bp = buf1 + (size_t)MPAD * 128;        // 5 * 16384 packed weights
  float* fbase = (float*)(Bp + 5 * 16384);
  float* dis = fbase;                            // [NB] pad 50048
  float* partial = dis + 50048;                  // [3125*256]
  float* partial2 = partial + (size_t)GATHER_BLKS * 256;  // [125*256]
  float* biasb = partial2 + RED_L1_BLKS * 256;   // [5*128]
  float* g = biasb + 640;                        // [NG*128]
  int* cnt = (int*)(g + (size_t)NG * 128);       // [NB]
  int* row_ptr = cnt + NB;                       // [NB+1] pad 50008
  int* rank = row_ptr + 50008;                   // [NE]
  int* e_src = rank + NE;                        // [NE]
  int* bsum = e_src + NE;                        // [256]
  int* boffs = bsum + 256;                       // [256]
  int* g_start = boffs + 256;                    // [NG+1]

  const int* src = ei;
  const int* dst = ei + NE;

  ushort* Bp0 = Bp;              // lin (K=64)
  ushort* Bp1 = Bp + 16384;      // conv0
  ushort* Bp2 = Bp + 2 * 16384;  // conv1 (BN0 folded)
  ushort* Bp3 = Bp + 3 * 16384;  // conv2 (BN1 folded)
  ushort* Bp4 = Bp + 4 * 16384;  // emb   (BN2 folded)
  float* bias0 = biasb;
  float* bias1 = biasb + 128;
  float* bias2 = biasb + 256;
  float* bias3 = biasb + 384;
  float* bias4 = biasb + 512;

  hipMemsetAsync(cnt, 0, NB * sizeof(int), stream);
  pack_init<<<24, 256, 0, stream>>>(lin_w, lin_b, conv_w, Bp0, Bp1, bias0,
                                    bias1);
  rank_kernel<<<EBLK, 256, 0, stream>>>(dst, cnt, rank);
  scan1<<<NBLK, 256, 0, stream>>>(cnt, row_ptr, bsum, dis);
  scan2<<<1, 256, 0, stream>>>(bsum, boffs);
  scan3<<<NBLK, 256, 0, stream>>>(row_ptr, boffs);
  fill2<<<EBLK + 8, 256, 0, stream>>>(src, dst, rank, row_ptr, e_src, batch,
                                      g_start);

  const int GB = (NB + 127) / 128;

  // linatoms (f32 A converted inline)
  gemm_mfma<false, true, false><<<GB, 256, 0, stream>>>(x, Bp0, bias0, nullptr,
                                                        buf0, NB, 64);

  // layer 0: transform (pre-scaled by dis) -> gather -> stats -> pack
  gemm_mfma<false, false, true><<<GB, 256, 0, stream>>>(buf0, Bp1, bias1, dis,
                                                        buf1, NB, 128);
  gather_conv<<<GATHER_BLKS, 256, 0, stream>>>(buf1, e_src, row_ptr, dis,
                                               conv_b, buf0, partial);
  reduce_l1<<<RED_L1_BLKS, 256, 0, stream>>>(partial, partial2);
  pack_final<<<16, 256, 0, stream>>>(conv_w + 16384, partial2, bn_g, bn_b,
                                     nullptr, Bp2, bias2);
  // layer 1
  gemm_mfma<false, false, true><<<GB, 256, 0, stream>>>(buf0, Bp2, bias2, dis,
                                                        buf1, NB, 128);
  gather_conv<<<GATHER_BLKS, 256, 0, stream>>>(buf1, e_src, row_ptr, dis,
                                               conv_b + 128, buf0, partial);
  reduce_l1<<<RED_L1_BLKS, 256, 0, stream>>>(partial, partial2);
  pack_final<<<16, 256, 0, stream>>>(conv_w + 2 * 16384, partial2, bn_g + 128,
                                     bn_b + 128, nullptr, Bp3, bias3);
  // layer 2
  gemm_mfma<false, false, true><<<GB, 256, 0, stream>>>(buf0, Bp3, bias3, dis,
                                                        buf1, NB, 128);
  gather_conv<<<GATHER_BLKS, 256, 0, stream>>>(buf1, e_src, row_ptr, dis,
                                               conv_b + 256, buf0, partial);
  reduce_l1<<<RED_L1_BLKS, 256, 0, stream>>>(partial, partial2);
  pack_final<<<16, 256, 0, stream>>>(emb_w, partial2, bn_g + 256, bn_b + 256,
                                     emb_b, Bp4, bias4);
  // emb + pool + head
  gemm_mfma<true, false, false><<<GB, 256, 0, stream>>>(buf0, Bp4, bias4,
                                                        nullptr, buf1, NB, 128);
  pool_gather<<<(NG * 16 + 255) / 256, 256, 0, stream>>>(buf1, g_start, g);
  head_kernel<<<(NG + 3) / 4, 128, 0, stream>>>(g, m1w, m1b, m2w, m2b, pw, pb,
                                                out);
}

// Round 11
// 288.853 us; speedup vs baseline: 1.0871x; 1.0871x over previous
//
#include <hip/hip_runtime.h>
#include <math.h>

#define NB 50000
#define NE 600000
#define NG 2000
#define ND 64
#define HID 128
#define BN_EPS 1e-5f
#define NBLK 196          // ceil(NB/256)
#define MPAD 50176        // padded rows for GEMM tiles
#define GATHER_BLKS 3125  // NB*16/256 exactly
#define RED_L1_BLKS 125   // 3125/25
#define EBLK 2344         // ceil(NE/256)

typedef __attribute__((ext_vector_type(8))) short bf16x8;
typedef __attribute__((ext_vector_type(4))) float f32x4;
typedef unsigned int uint;
typedef unsigned short ushort;

__device__ __forceinline__ ushort f2b(float f) {
  uint u = __builtin_bit_cast(uint, f);
  u = u + 0x7fffu + ((u >> 16) & 1u);  // RNE
  return (ushort)(u >> 16);
}
__device__ __forceinline__ float blo(uint u) {
  return __builtin_bit_cast(float, u << 16);
}
__device__ __forceinline__ float bhi(uint u) {
  return __builtin_bit_cast(float, u & 0xffff0000u);
}

// ---- pass 1: rank[e] = arrival index within dst bucket; cnt = in-degree ----
__global__ __launch_bounds__(256) void rank_kernel(const int* __restrict__ dst,
                                                   int* __restrict__ cnt,
                                                   int* __restrict__ rank) {
  int e = blockIdx.x * 256 + threadIdx.x;
  if (e < NE) rank[e] = atomicAdd(&cnt[dst[e]], 1);
}

// ---- prefix scan over cnt (multi-block) + dis fold -------------------------
__global__ __launch_bounds__(256) void scan1(const int* __restrict__ cnt,
                                             int* __restrict__ part,
                                             int* __restrict__ bsum,
                                             float* __restrict__ dis) {
  __shared__ int tmp[256];
  int tid = threadIdx.x;
  int i = blockIdx.x * 256 + tid;
  int v = (i < NB) ? cnt[i] : 0;
  if (i < NB) dis[i] = rsqrtf((float)(v + 1));  // +1 self-loop
  tmp[tid] = v;
  __syncthreads();
  for (int off = 1; off < 256; off <<= 1) {
    int t = (tid >= off) ? tmp[tid - off] : 0;
    __syncthreads();
    tmp[tid] += t;
    __syncthreads();
  }
  if (i < NB) part[i] = tmp[tid] - v;
  if (tid == 255) bsum[blockIdx.x] = tmp[255];
}

// scan2 merged in: each block tree-reduces bsum[0..bid-1] (<=196 ints, L2-hot)
__global__ __launch_bounds__(256) void scan3(int* __restrict__ part,
                                             const int* __restrict__ bsum) {
  __shared__ int red[256];
  int tid = threadIdx.x, bid = blockIdx.x;
  red[tid] = (tid < bid) ? bsum[tid] : 0;  // bid <= 195 < 256
  __syncthreads();
  for (int st = 128; st >= 1; st >>= 1) {
    if (tid < st) red[tid] += red[tid + st];
    __syncthreads();
  }
  int boff = red[0];
  int i = bid * 256 + tid;
  if (i < NB) part[i] += boff;
  if (i == 0) part[NB] = NE;
}

// ---- pass 2: atomic-free CSR fill (4B payload) + graph_bounds tail ---------
__global__ __launch_bounds__(256) void fill2(const int* __restrict__ src,
                                             const int* __restrict__ dst,
                                             const int* __restrict__ rank,
                                             const int* __restrict__ row_ptr,
                                             int* __restrict__ e_src,
                                             const int* __restrict__ batch,
                                             int* __restrict__ g_start) {
  int bid = blockIdx.x;
  int tid = threadIdx.x;
  if (bid < EBLK) {
    int e = bid * 256 + tid;
    if (e >= NE) return;
    int s = src[e], d = dst[e];
    e_src[row_ptr[d] + rank[e]] = s;
  } else {
    int g = (bid - EBLK) * 256 + tid;
    if (g > NG) return;
    if (g == NG) { g_start[NG] = NB; return; }
    int lo = 0, hi = NB;
    while (lo < hi) {
      int mid = (lo + hi) >> 1;
      if (batch[mid] < g) lo = mid + 1; else hi = mid;
    }
    g_start[g] = lo;
  }
}

// ---- weight packing helper -------------------------------------------------
// Bp layout: ((nf*nkf+kf)*64+lane)*8+j -> W[kf*32+(lane>>4)*8+j][nf*16+(lane&15)]
__device__ __forceinline__ void pack_slice(const float* __restrict__ W, int K,
                                           const float* __restrict__ a_s,
                                           ushort* __restrict__ Bp, int slice,
                                           int tid) {
  int nkf = K >> 5;
  int i = slice * 1024 + tid;
  int total = nkf * 4096;
#pragma unroll 4
  for (int u = 0; u < 4; u++, i += 256) {
    if (i < total) {
      int j = i & 7;
      int lane = (i >> 3) & 63;
      int rem = i >> 9;
      int kf = rem % nkf;
      int nf = rem / nkf;
      int k = kf * 32 + (lane >> 4) * 8 + j;
      int col = nf * 16 + (lane & 15);
      float a = a_s ? a_s[k] : 1.f;
      Bp[i] = f2b(a * W[k * 128 + col]);
    }
  }
}

// ---- initial packing: lin (K=64, blocks 0-7) + conv0 (blocks 8-23) ---------
__global__ __launch_bounds__(256) void pack_init(const float* __restrict__ lin_w,
                                                 const float* __restrict__ lin_b,
                                                 const float* __restrict__ conv_w0,
                                                 ushort* __restrict__ Bp0,
                                                 ushort* __restrict__ Bp1,
                                                 float* __restrict__ bias0,
                                                 float* __restrict__ bias1) {
  int bid = blockIdx.x, tid = threadIdx.x;
  if (bid == 0 && tid < 128) {
    bias0[tid] = lin_b[tid];
    bias1[tid] = 0.f;
  }
  if (bid < 8)
    pack_slice(lin_w, 64, nullptr, Bp0, bid, tid);
  else
    pack_slice(conv_w0, 128, nullptr, Bp1, bid - 8, tid);
}

// ---- stats level-1 reduce: [3125][256] -> [125][256] -----------------------
__global__ __launch_bounds__(256) void reduce_l1(const float* __restrict__ partial,
                                                 float* __restrict__ partial2) {
  int tid = threadIdx.x;
  int b = blockIdx.x;
  float s = 0.f;
#pragma unroll 5
  for (int r = b * 25; r < b * 25 + 25; r++)
    s += partial[(size_t)r * 256 + tid];
  partial2[(size_t)b * 256 + tid] = s;
}

// ---- fused finalize (125-row reduce, L2-hot) + BN fold + pack (16 blocks) --
__global__ __launch_bounds__(256) void pack_final(
    const float* __restrict__ W, const float* __restrict__ partial2,
    const float* __restrict__ gamma, const float* __restrict__ beta,
    const float* __restrict__ bias_in, ushort* __restrict__ Bp,
    float* __restrict__ bias_out) {
  __shared__ float a_s[128], b_s[128];
  __shared__ float red[256];
  int t = threadIdx.x;
  float s = 0.f;
#pragma unroll 5
  for (int r = 0; r < RED_L1_BLKS; r++) s += partial2[(size_t)r * 256 + t];
  red[t] = s;
  __syncthreads();
  if (t < 128) {
    float mu = red[t] * (1.f / NB);
    float var = red[128 + t] * (1.f / NB) - mu * mu;
    float a = gamma[t] * rsqrtf(var + BN_EPS);
    a_s[t] = a;
    b_s[t] = beta[t] - mu * a;
  }
  __syncthreads();
  if (blockIdx.x == 0 && t < 128) {
    float acc = bias_in ? bias_in[t] : 0.f;
    for (int k = 0; k < 128; k++) acc += b_s[k] * W[k * 128 + t];
    bias_out[t] = acc;
  }
  pack_slice(W, 128, a_s, Bp, blockIdx.x, t);
}

// ---- bf16 MFMA GEMM: C[M,128] = A[M,K] @ Bp (+bias, opt relu) --------------
template <bool RELU, bool F32A>
__global__ __launch_bounds__(256) void gemm_mfma(const void* __restrict__ Av,
                                                 const ushort* __restrict__ Bp,
                                                 const float* __restrict__ bias,
                                                 ushort* __restrict__ C, int M,
                                                 int K) {
  __shared__ ushort Blds[16384];
  const int tid = threadIdx.x;
  const int lane = tid & 63;
  const int w = tid >> 6;
  const int nkf = K >> 5;
  for (int i = tid; i < nkf * 512; i += 256)
    reinterpret_cast<uint4*>(Blds)[i] = reinterpret_cast<const uint4*>(Bp)[i];
  __syncthreads();

  const int rbase = blockIdx.x * 128 + w * 32;
  f32x4 acc[2][8];
#pragma unroll
  for (int m = 0; m < 2; m++)
#pragma unroll
    for (int n = 0; n < 8; n++) acc[m][n] = (f32x4){0.f, 0.f, 0.f, 0.f};

  const int arow0 = rbase + (lane & 15);
  const int arow1 = arow0 + 16;
  const int ra0 = F32A ? (arow0 < M ? arow0 : M - 1) : arow0;
  const int ra1 = F32A ? (arow1 < M ? arow1 : M - 1) : arow1;
  const int acol = (lane >> 4) * 8;
#pragma unroll 4
  for (int kf = 0; kf < nkf; kf++) {
    bf16x8 a0, a1;
    if constexpr (F32A) {
      const float* Af = (const float*)Av;
      const float4* p0 =
          reinterpret_cast<const float4*>(Af + (size_t)ra0 * K + kf * 32 + acol);
      const float4* p1 =
          reinterpret_cast<const float4*>(Af + (size_t)ra1 * K + kf * 32 + acol);
      float4 u0 = p0[0], u1 = p0[1], v0 = p1[0], v1 = p1[1];
      a0[0] = (short)f2b(u0.x); a0[1] = (short)f2b(u0.y);
      a0[2] = (short)f2b(u0.z); a0[3] = (short)f2b(u0.w);
      a0[4] = (short)f2b(u1.x); a0[5] = (short)f2b(u1.y);
      a0[6] = (short)f2b(u1.z); a0[7] = (short)f2b(u1.w);
      a1[0] = (short)f2b(v0.x); a1[1] = (short)f2b(v0.y);
      a1[2] = (short)f2b(v0.z); a1[3] = (short)f2b(v0.w);
      a1[4] = (short)f2b(v1.x); a1[5] = (short)f2b(v1.y);
      a1[6] = (short)f2b(v1.z); a1[7] = (short)f2b(v1.w);
    } else {
      const ushort* A = (const ushort*)Av;
      a0 = *reinterpret_cast<const bf16x8*>(A + (size_t)ra0 * K + kf * 32 + acol);
      a1 = *reinterpret_cast<const bf16x8*>(A + (size_t)ra1 * K + kf * 32 + acol);
    }
#pragma unroll
    for (int nf = 0; nf < 8; nf++) {
      bf16x8 b = *reinterpret_cast<const bf16x8*>(
          &Blds[((nf * nkf + kf) * 64 + lane) * 8]);
      acc[0][nf] = __builtin_amdgcn_mfma_f32_16x16x32_bf16(a0, b, acc[0][nf], 0, 0, 0);
      acc[1][nf] = __builtin_amdgcn_mfma_f32_16x16x32_bf16(a1, b, acc[1][nf], 0, 0, 0);
    }
  }

#pragma unroll
  for (int m = 0; m < 2; m++) {
    int row0 = rbase + m * 16 + (lane >> 4) * 4;
#pragma unroll
    for (int nf = 0; nf < 8; nf++) {
      int col = nf * 16 + (lane & 15);
      float bv = bias[col];
#pragma unroll
      for (int r = 0; r < 4; r++) {
        int row = row0 + r;
        if (row < M) {
          float v = acc[m][nf][r] + bv;
          if (RELU) v = fmaxf(v, 0.f);
          C[(size_t)row * 128 + col] = f2b(v);
        }
      }
    }
  }
}

// ---- conv aggregation: CSR gather (4-edge unroll, 2 acc chains) ------------
__global__ __launch_bounds__(256) void gather_conv(
    const ushort* __restrict__ h, const int* __restrict__ e_src,
    const int* __restrict__ row_ptr, const float* __restrict__ dis,
    const float* __restrict__ bias, ushort* __restrict__ y,
    float* __restrict__ partial) {
  __shared__ float red[2048];
  int tid = threadIdx.x;
  int gid = blockIdx.x * 256 + tid;
  int v = gid >> 4;  // grid == NB*16 exactly
  int c8 = gid & 15;
  const uint4* h4 = reinterpret_cast<const uint4*>(h);
  float sv = dis[v];
  float ss = sv * sv;
  uint4 hv = h4[(size_t)v * 16 + c8];
  float acc[8], acc2[8];
  acc[0] = bias[c8 * 8 + 0] + blo(hv.x) * ss;
  acc[1] = bias[c8 * 8 + 1] + bhi(hv.x) * ss;
  acc[2] = bias[c8 * 8 + 2] + blo(hv.y) * ss;
  acc[3] = bias[c8 * 8 + 3] + bhi(hv.y) * ss;
  acc[4] = bias[c8 * 8 + 4] + blo(hv.z) * ss;
  acc[5] = bias[c8 * 8 + 5] + bhi(hv.z) * ss;
  acc[6] = bias[c8 * 8 + 6] + blo(hv.w) * ss;
  acc[7] = bias[c8 * 8 + 7] + bhi(hv.w) * ss;
#pragma unroll
  for (int j = 0; j < 8; j++) acc2[j] = 0.f;
  int beg = row_ptr[v], end = row_ptr[v + 1];
  int e = beg;
  for (; e + 4 <= end; e += 4) {
    int s0 = e_src[e], s1 = e_src[e + 1], s2 = e_src[e + 2], s3 = e_src[e + 3];
    uint4 q0 = h4[(size_t)s0 * 16 + c8];
    uint4 q1 = h4[(size_t)s1 * 16 + c8];
    uint4 q2 = h4[(size_t)s2 * 16 + c8];
    uint4 q3 = h4[(size_t)s3 * 16 + c8];
    float w0 = dis[s0] * sv, w1 = dis[s1] * sv;
    float w2 = dis[s2] * sv, w3 = dis[s3] * sv;
    acc[0] += blo(q0.x) * w0; acc2[0] += blo(q1.x) * w1;
    acc[1] += bhi(q0.x) * w0; acc2[1] += bhi(q1.x) * w1;
    acc[2] += blo(q0.y) * w0; acc2[2] += blo(q1.y) * w1;
    acc[3] += bhi(q0.y) * w0; acc2[3] += bhi(q1.y) * w1;
    acc[4] += blo(q0.z) * w0; acc2[4] += blo(q1.z) * w1;
    acc[5] += bhi(q0.z) * w0; acc2[5] += bhi(q1.z) * w1;
    acc[6] += blo(q0.w) * w0; acc2[6] += blo(q1.w) * w1;
    acc[7] += bhi(q0.w) * w0; acc2[7] += bhi(q1.w) * w1;
    acc[0] += blo(q2.x) * w2; acc2[0] += blo(q3.x) * w3;
    acc[1] += bhi(q2.x) * w2; acc2[1] += bhi(q3.x) * w3;
    acc[2] += blo(q2.y) * w2; acc2[2] += blo(q3.y) * w3;
    acc[3] += bhi(q2.y) * w2; acc2[3] += bhi(q3.y) * w3;
    acc[4] += blo(q2.z) * w2; acc2[4] += blo(q3.z) * w3;
    acc[5] += bhi(q2.z) * w2; acc2[5] += bhi(q3.z) * w3;
    acc[6] += blo(q2.w) * w2; acc2[6] += blo(q3.w) * w3;
    acc[7] += bhi(q2.w) * w2; acc2[7] += bhi(q3.w) * w3;
  }
  for (; e < end; ++e) {
    int s0 = e_src[e];
    uint4 q0 = h4[(size_t)s0 * 16 + c8];
    float w0 = dis[s0] * sv;
    acc[0] += blo(q0.x) * w0; acc[1] += bhi(q0.x) * w0;
    acc[2] += blo(q0.y) * w0; acc[3] += bhi(q0.y) * w0;
    acc[4] += blo(q0.z) * w0; acc[5] += bhi(q0.z) * w0;
    acc[6] += blo(q0.w) * w0; acc[7] += bhi(q0.w) * w0;
  }
#pragma unroll
  for (int j = 0; j < 8; j++) acc[j] = fmaxf(acc[j] + acc2[j], 0.f);
  uint4 o;
  o.x = (uint)f2b(acc[0]) | ((uint)f2b(acc[1]) << 16);
  o.y = (uint)f2b(acc[2]) | ((uint)f2b(acc[3]) << 16);
  o.z = (uint)f2b(acc[4]) | ((uint)f2b(acc[5]) << 16);
  o.w = (uint)f2b(acc[6]) | ((uint)f2b(acc[7]) << 16);
  reinterpret_cast<uint4*>(y)[(size_t)v * 16 + c8] = o;

  // fused per-block stats partials (no atomics)
#pragma unroll
  for (int j = 0; j < 8; j++) red[tid * 8 + j] = acc[j];
  __syncthreads();
  for (int st = 128; st >= 16; st >>= 1) {
    if (tid < st)
#pragma unroll
      for (int j = 0; j < 8; j++) red[tid * 8 + j] += red[(tid + st) * 8 + j];
    __syncthreads();
  }
  if (tid < 16)
#pragma unroll
    for (int j = 0; j < 8; j++)
      partial[(size_t)blockIdx.x * 256 + tid * 8 + j] = red[tid * 8 + j];
  __syncthreads();
#pragma unroll
  for (int j = 0; j < 8; j++) red[tid * 8 + j] = acc[j] * acc[j];
  __syncthreads();
  for (int st = 128; st >= 16; st >>= 1) {
    if (tid < st)
#pragma unroll
      for (int j = 0; j < 8; j++) red[tid * 8 + j] += red[(tid + st) * 8 + j];
    __syncthreads();
  }
  if (tid < 16)
#pragma unroll
    for (int j = 0; j < 8; j++)
      partial[(size_t)blockIdx.x * 256 + 128 + tid * 8 + j] = red[tid * 8 + j];
}

// ---- pooling: vectorized segmented gather (16 lanes/graph, uint4) ----------
__global__ __launch_bounds__(256) void pool_gather(const ushort* __restrict__ emb,
                                                   const int* __restrict__ g_start,
                                                   float* __restrict__ g) {
  int gid = blockIdx.x * 256 + threadIdx.x;
  int gr = gid >> 4;
  if (gr >= NG) return;
  int c8 = gid & 15;
  const uint4* e4 = reinterpret_cast<const uint4*>(emb);
  float acc[8];
#pragma unroll
  for (int j = 0; j < 8; j++) acc[j] = 0.f;
  int beg = g_start[gr], end = g_start[gr + 1];
  for (int v = beg; v < end; ++v) {
    uint4 q = e4[(size_t)v * 16 + c8];
    acc[0] += blo(q.x); acc[1] += bhi(q.x);
    acc[2] += blo(q.y); acc[3] += bhi(q.y);
    acc[4] += blo(q.z); acc[5] += bhi(q.z);
    acc[6] += blo(q.w); acc[7] += bhi(q.w);
  }
  float4* gp = reinterpret_cast<float4*>(g + (size_t)gr * 128 + c8 * 8);
  gp[0] = make_float4(acc[0], acc[1], acc[2], acc[3]);
  gp[1] = make_float4(acc[4], acc[5], acc[6], acc[7]);
}

// ---- head: 128->64->32->2 MLP, 4 graphs/block (500 blocks), LDS weights ----
__global__ __launch_bounds__(128) void head_kernel(
    const float* __restrict__ g, const float* __restrict__ w1,
    const float* __restrict__ b1, const float* __restrict__ w2,
    const float* __restrict__ b2, const float* __restrict__ wp,
    const float* __restrict__ bp, float* __restrict__ out) {
  __shared__ float w1s[128 * 64];
  __shared__ float w2s[64 * 32];
  __shared__ float wps[64];
  __shared__ float sg[128], ph[128], sh1[64], sh2[32];
  int tid = threadIdx.x;
  for (int i = tid; i < 2048; i += 128)
    reinterpret_cast<float4*>(w1s)[i] = reinterpret_cast<const float4*>(w1)[i];
  for (int i = tid; i < 512; i += 128)
    reinterpret_cast<float4*>(w2s)[i] = reinterpret_cast<const float4*>(w2)[i];
  if (tid < 64) wps[tid] = wp[tid];
  __syncthreads();

  for (int gi = 0; gi < 4; gi++) {
    int gid = blockIdx.x * 4 + gi;
    if (gid >= NG) break;
    sg[tid] = g[(size_t)gid * 128 + tid];
    __syncthreads();
    {
      int o = tid & 63, h = tid >> 6;
      float acc = 0.f;
#pragma unroll 8
      for (int k = 0; k < 64; k++)
        acc += sg[h * 64 + k] * w1s[(h * 64 + k) * 64 + o];
      ph[tid] = acc;
    }
    __syncthreads();
    if (tid < 64) sh1[tid] = fmaxf(b1[tid] + ph[tid] + ph[tid + 64], 0.f);
    __syncthreads();
    {
      int o = tid & 31, q = tid >> 5;
      float acc = 0.f;
#pragma unroll 8
      for (int k = 0; k < 16; k++)
        acc += sh1[q * 16 + k] * w2s[(q * 16 + k) * 32 + o];
      ph[tid] = acc;
    }
    __syncthreads();
    if (tid < 32)
      sh2[tid] = fmaxf(
          b2[tid] + ph[tid] + ph[tid + 32] + ph[tid + 64] + ph[tid + 96], 0.f);
    __syncthreads();
    if (tid < 2) {
      float acc = bp[tid];
#pragma unroll
      for (int k = 0; k < 32; k++) acc += sh2[k] * wps[k * 2 + tid];
      out[(size_t)gid * 2 + tid] = acc;
    }
    __syncthreads();
  }
}

extern "C" void kernel_launch(void* const* d_in, const int* in_sizes, int n_in,
                              void* d_out, int out_size, void* d_ws,
                              size_t ws_size, hipStream_t stream) {
  const float* x = (const float*)d_in[0];
  const int* ei = (const int*)d_in[1];
  const int* batch = (const int*)d_in[2];
  const float* lin_w = (const float*)d_in[3];
  const float* lin_b = (const float*)d_in[4];
  const float* conv_w = (const float*)d_in[5];
  const float* conv_b = (const float*)d_in[6];
  const float* bn_g = (const float*)d_in[7];
  const float* bn_b = (const float*)d_in[8];
  const float* emb_w = (const float*)d_in[9];
  const float* emb_b = (const float*)d_in[10];
  const float* m1w = (const float*)d_in[11];
  const float* m1b = (const float*)d_in[12];
  const float* m2w = (const float*)d_in[13];
  const float* m2b = (const float*)d_in[14];
  const float* pw = (const float*)d_in[15];
  const float* pb = (const float*)d_in[16];
  float* out = (float*)d_out;

  ushort* buf0 = (ushort*)d_ws;                  // [MPAD,128] bf16
  ushort* buf1 = buf0 + (size_t)MPAD * 128;      // [MPAD,128] bf16
  ushort* Bp = buf1 + (size_t)MPAD * 128;        // 5 * 16384 packed weights
  float* fbase = (float*)(Bp + 5 * 16384);
  float* dis = fbase;                            // [NB] pad 50048
  float* partial = dis + 50048;                  // [3125*256]
  float* partial2 = partial + (size_t)GATHER_BLKS * 256;  // [125*256]
  float* biasb = partial2 + RED_L1_BLKS * 256;   // [5*128]
  float* g = biasb + 640;                        // [NG*128]
  int* cnt = (int*)(g + (size_t)NG * 128);       // [NB]
  int* row_ptr = cnt + NB;                       // [NB+1] pad 50008
  int* rank = row_ptr + 50008;                   // [NE]
  int* e_src = rank + NE;                        // [NE]
  int* bsum = e_src + NE;                        // [256]
  int* g_start = bsum + 256;                     // [NG+1]

  const int* src = ei;
  const int* dst = ei + NE;

  ushort* Bp0 = Bp;              // lin (K=64)
  ushort* Bp1 = Bp + 16384;      // conv0
  ushort* Bp2 = Bp + 2 * 16384;  // conv1 (BN0 folded)
  ushort* Bp3 = Bp + 3 * 16384;  // conv2 (BN1 folded)
  ushort* Bp4 = Bp + 4 * 16384;  // emb   (BN2 folded)
  float* bias0 = biasb;
  float* bias1 = biasb + 128;
  float* bias2 = biasb + 256;
  float* bias3 = biasb + 384;
  float* bias4 = biasb + 512;

  hipMemsetAsync(cnt, 0, NB * sizeof(int), stream);
  pack_init<<<24, 256, 0, stream>>>(lin_w, lin_b, conv_w, Bp0, Bp1, bias0,
                                    bias1);
  rank_kernel<<<EBLK, 256, 0, stream>>>(dst, cnt, rank);
  scan1<<<NBLK, 256, 0, stream>>>(cnt, row_ptr, bsum, dis);
  scan3<<<NBLK, 256, 0, stream>>>(row_ptr, bsum);
  fill2<<<EBLK + 8, 256, 0, stream>>>(src, dst, rank, row_ptr, e_src, batch,
                                      g_start);

  const int GB = (NB + 127) / 128;

  // linatoms (f32 A converted inline)
  gemm_mfma<false, true><<<GB, 256, 0, stream>>>(x, Bp0, bias0, buf0, NB, 64);

  // layer 0
  gemm_mfma<false, false><<<GB, 256, 0, stream>>>(buf0, Bp1, bias1, buf1, NB, 128);
  gather_conv<<<GATHER_BLKS, 256, 0, stream>>>(buf1, e_src, row_ptr, dis,
                                               conv_b, buf0, partial);
  reduce_l1<<<RED_L1_BLKS, 256, 0, stream>>>(partial, partial2);
  pack_final<<<16, 256, 0, stream>>>(conv_w + 16384, partial2, bn_g, bn_b,
                                     nullptr, Bp2, bias2);
  // layer 1
  gemm_mfma<false, false><<<GB, 256, 0, stream>>>(buf0, Bp2, bias2, buf1, NB, 128);
  gather_conv<<<GATHER_BLKS, 256, 0, stream>>>(buf1, e_src, row_ptr, dis,
                                               conv_b + 128, buf0, partial);
  reduce_l1<<<RED_L1_BLKS, 256, 0, stream>>>(partial, partial2);
  pack_final<<<16, 256, 0, stream>>>(conv_w + 2 * 16384, partial2, bn_g + 128,
                                     bn_b + 128, nullptr, Bp3, bias3);
  // layer 2
  gemm_mfma<false, false><<<GB, 256, 0, stream>>>(buf0, Bp3, bias3, buf1, NB, 128);
  gather_conv<<<GATHER_BLKS, 256, 0, stream>>>(buf1, e_src, row_ptr, dis,
                                               conv_b + 256, buf0, partial);
  reduce_l1<<<RED_L1_BLKS, 256, 0, stream>>>(partial, partial2);
  pack_final<<<16, 256, 0, stream>>>(emb_w, partial2, bn_g + 256, bn_b + 256,
                                     emb_b, Bp4, bias4);
  // emb + pool + head
  gemm_mfma<true, false><<<GB, 256, 0, stream>>>(buf0, Bp4, bias4, buf1, NB, 128);
  pool_gather<<<(NG * 16 + 255) / 256, 256, 0, stream>>>(buf1, g_start, g);
  head_kernel<<<(NG + 3) / 4, 128, 0, stream>>>(g, m1w, m1b, m2w, m2b, pw, pb,
                                                out);
}

// Round 12
// 286.217 us; speedup vs baseline: 1.0972x; 1.0092x over previous
//
#include <hip/hip_runtime.h>
#include <math.h>

#define NB 50000
#define NE 600000
#define NG 2000
#define ND 64
#define HID 128
#define BN_EPS 1e-5f
#define NBLK 196          // ceil(NB/256)
#define MPAD 50176        // padded rows for GEMM tiles
#define GATHER_BLKS 3125  // NB*16/256 exactly
#define RED_L1_BLKS 125   // 3125/25
#define EBLK 2344         // ceil(NE/256)

typedef __attribute__((ext_vector_type(8))) short bf16x8;
typedef __attribute__((ext_vector_type(4))) float f32x4;
typedef unsigned int uint;
typedef unsigned short ushort;

__device__ __forceinline__ ushort f2b(float f) {
  uint u = __builtin_bit_cast(uint, f);
  u = u + 0x7fffu + ((u >> 16) & 1u);  // RNE
  return (ushort)(u >> 16);
}
__device__ __forceinline__ float blo(uint u) {
  return __builtin_bit_cast(float, u << 16);
}
__device__ __forceinline__ float bhi(uint u) {
  return __builtin_bit_cast(float, u & 0xffff0000u);
}

// ---- pass 1: rank[e] = arrival index within dst bucket (ushort) ------------
__global__ __launch_bounds__(256) void rank_kernel(const int* __restrict__ dst,
                                                   int* __restrict__ cnt,
                                                   ushort* __restrict__ rank) {
  int e = blockIdx.x * 256 + threadIdx.x;
  if (e < NE) rank[e] = (ushort)atomicAdd(&cnt[dst[e]], 1);
}

// ---- prefix scan over cnt (multi-block) + dis fold -------------------------
__global__ __launch_bounds__(256) void scan1(const int* __restrict__ cnt,
                                             int* __restrict__ part,
                                             int* __restrict__ bsum,
                                             float* __restrict__ dis) {
  __shared__ int tmp[256];
  int tid = threadIdx.x;
  int i = blockIdx.x * 256 + tid;
  int v = (i < NB) ? cnt[i] : 0;
  if (i < NB) dis[i] = rsqrtf((float)(v + 1));  // +1 self-loop
  tmp[tid] = v;
  __syncthreads();
  for (int off = 1; off < 256; off <<= 1) {
    int t = (tid >= off) ? tmp[tid - off] : 0;
    __syncthreads();
    tmp[tid] += t;
    __syncthreads();
  }
  if (i < NB) part[i] = tmp[tid] - v;
  if (tid == 255) bsum[blockIdx.x] = tmp[255];
}

// scan2 merged in: each block tree-reduces bsum[0..bid-1] (<=196 ints, L2-hot)
__global__ __launch_bounds__(256) void scan3(int* __restrict__ part,
                                             const int* __restrict__ bsum) {
  __shared__ int red[256];
  int tid = threadIdx.x, bid = blockIdx.x;
  red[tid] = (tid < bid) ? bsum[tid] : 0;  // bid <= 195 < 256
  __syncthreads();
  for (int st = 128; st >= 1; st >>= 1) {
    if (tid < st) red[tid] += red[tid + st];
    __syncthreads();
  }
  int boff = red[0];
  int i = bid * 256 + tid;
  if (i < NB) part[i] += boff;
  if (i == 0) part[NB] = NE;
}

// ---- pass 2: atomic-free CSR fill (2B payload) + graph_bounds tail ---------
__global__ __launch_bounds__(256) void fill2(const int* __restrict__ src,
                                             const int* __restrict__ dst,
                                             const ushort* __restrict__ rank,
                                             const int* __restrict__ row_ptr,
                                             ushort* __restrict__ e_src,
                                             const int* __restrict__ batch,
                                             int* __restrict__ g_start) {
  int bid = blockIdx.x;
  int tid = threadIdx.x;
  if (bid < EBLK) {
    int e = bid * 256 + tid;
    if (e >= NE) return;
    int s = src[e], d = dst[e];
    e_src[row_ptr[d] + (int)rank[e]] = (ushort)s;
  } else {
    int g = (bid - EBLK) * 256 + tid;
    if (g > NG) return;
    if (g == NG) { g_start[NG] = NB; return; }
    int lo = 0, hi = NB;
    while (lo < hi) {
      int mid = (lo + hi) >> 1;
      if (batch[mid] < g) lo = mid + 1; else hi = mid;
    }
    g_start[g] = lo;
  }
}

// ---- weight packing helper -------------------------------------------------
// Bp layout: ((nf*nkf+kf)*64+lane)*8+j -> W[kf*32+(lane>>4)*8+j][nf*16+(lane&15)]
__device__ __forceinline__ void pack_slice(const float* __restrict__ W, int K,
                                           const float* __restrict__ a_s,
                                           ushort* __restrict__ Bp, int slice,
                                           int tid) {
  int nkf = K >> 5;
  int i = slice * 1024 + tid;
  int total = nkf * 4096;
#pragma unroll 4
  for (int u = 0; u < 4; u++, i += 256) {
    if (i < total) {
      int j = i & 7;
      int lane = (i >> 3) & 63;
      int rem = i >> 9;
      int kf = rem % nkf;
      int nf = rem / nkf;
      int k = kf * 32 + (lane >> 4) * 8 + j;
      int col = nf * 16 + (lane & 15);
      float a = a_s ? a_s[k] : 1.f;
      Bp[i] = f2b(a * W[k * 128 + col]);
    }
  }
}

// ---- initial packing + cnt zeroing -----------------------------------------
// blocks 0-7: lin pack; 8-23: conv0 pack; 24-219: zero cnt[]
__global__ __launch_bounds__(256) void pack_init(const float* __restrict__ lin_w,
                                                 const float* __restrict__ lin_b,
                                                 const float* __restrict__ conv_w0,
                                                 ushort* __restrict__ Bp0,
                                                 ushort* __restrict__ Bp1,
                                                 float* __restrict__ bias0,
                                                 float* __restrict__ bias1,
                                                 int* __restrict__ cnt) {
  int bid = blockIdx.x, tid = threadIdx.x;
  if (bid == 0 && tid < 128) {
    bias0[tid] = lin_b[tid];
    bias1[tid] = 0.f;
  }
  if (bid < 8) {
    pack_slice(lin_w, 64, nullptr, Bp0, bid, tid);
  } else if (bid < 24) {
    pack_slice(conv_w0, 128, nullptr, Bp1, bid - 8, tid);
  } else {
    int i = (bid - 24) * 256 + tid;
    if (i < NB) cnt[i] = 0;
  }
}

// ---- stats level-1 reduce: [3125][256] -> [125][256] -----------------------
__global__ __launch_bounds__(256) void reduce_l1(const float* __restrict__ partial,
                                                 float* __restrict__ partial2) {
  int tid = threadIdx.x;
  int b = blockIdx.x;
  float s = 0.f;
#pragma unroll 5
  for (int r = b * 25; r < b * 25 + 25; r++)
    s += partial[(size_t)r * 256 + tid];
  partial2[(size_t)b * 256 + tid] = s;
}

// ---- fused finalize (125-row reduce, L2-hot) + BN fold + pack (16 blocks) --
__global__ __launch_bounds__(256) void pack_final(
    const float* __restrict__ W, const float* __restrict__ partial2,
    const float* __restrict__ gamma, const float* __restrict__ beta,
    const float* __restrict__ bias_in, ushort* __restrict__ Bp,
    float* __restrict__ bias_out) {
  __shared__ float a_s[128], b_s[128];
  __shared__ float red[256];
  int t = threadIdx.x;
  float s = 0.f;
#pragma unroll 5
  for (int r = 0; r < RED_L1_BLKS; r++) s += partial2[(size_t)r * 256 + t];
  red[t] = s;
  __syncthreads();
  if (t < 128) {
    float mu = red[t] * (1.f / NB);
    float var = red[128 + t] * (1.f / NB) - mu * mu;
    float a = gamma[t] * rsqrtf(var + BN_EPS);
    a_s[t] = a;
    b_s[t] = beta[t] - mu * a;
  }
  __syncthreads();
  if (blockIdx.x == 0 && t < 128) {
    float acc = bias_in ? bias_in[t] : 0.f;
    for (int k = 0; k < 128; k++) acc += b_s[k] * W[k * 128 + t];
    bias_out[t] = acc;
  }
  pack_slice(W, 128, a_s, Bp, blockIdx.x, t);
}

// ---- bf16 MFMA GEMM: C[M,128] = A[M,K] @ Bp (+bias, opt relu) --------------
template <bool RELU, bool F32A>
__global__ __launch_bounds__(256) void gemm_mfma(const void* __restrict__ Av,
                                                 const ushort* __restrict__ Bp,
                                                 const float* __restrict__ bias,
                                                 ushort* __restrict__ C, int M,
                                                 int K) {
  __shared__ ushort Blds[16384];
  const int tid = threadIdx.x;
  const int lane = tid & 63;
  const int w = tid >> 6;
  const int nkf = K >> 5;
  for (int i = tid; i < nkf * 512; i += 256)
    reinterpret_cast<uint4*>(Blds)[i] = reinterpret_cast<const uint4*>(Bp)[i];
  __syncthreads();

  const int rbase = blockIdx.x * 128 + w * 32;
  f32x4 acc[2][8];
#pragma unroll
  for (int m = 0; m < 2; m++)
#pragma unroll
    for (int n = 0; n < 8; n++) acc[m][n] = (f32x4){0.f, 0.f, 0.f, 0.f};

  const int arow0 = rbase + (lane & 15);
  const int arow1 = arow0 + 16;
  const int ra0 = F32A ? (arow0 < M ? arow0 : M - 1) : arow0;
  const int ra1 = F32A ? (arow1 < M ? arow1 : M - 1) : arow1;
  const int acol = (lane >> 4) * 8;
#pragma unroll 4
  for (int kf = 0; kf < nkf; kf++) {
    bf16x8 a0, a1;
    if constexpr (F32A) {
      const float* Af = (const float*)Av;
      const float4* p0 =
          reinterpret_cast<const float4*>(Af + (size_t)ra0 * K + kf * 32 + acol);
      const float4* p1 =
          reinterpret_cast<const float4*>(Af + (size_t)ra1 * K + kf * 32 + acol);
      float4 u0 = p0[0], u1 = p0[1], v0 = p1[0], v1 = p1[1];
      a0[0] = (short)f2b(u0.x); a0[1] = (short)f2b(u0.y);
      a0[2] = (short)f2b(u0.z); a0[3] = (short)f2b(u0.w);
      a0[4] = (short)f2b(u1.x); a0[5] = (short)f2b(u1.y);
      a0[6] = (short)f2b(u1.z); a0[7] = (short)f2b(u1.w);
      a1[0] = (short)f2b(v0.x); a1[1] = (short)f2b(v0.y);
      a1[2] = (short)f2b(v0.z); a1[3] = (short)f2b(v0.w);
      a1[4] = (short)f2b(v1.x); a1[5] = (short)f2b(v1.y);
      a1[6] = (short)f2b(v1.z); a1[7] = (short)f2b(v1.w);
    } else {
      const ushort* A = (const ushort*)Av;
      a0 = *reinterpret_cast<const bf16x8*>(A + (size_t)ra0 * K + kf * 32 + acol);
      a1 = *reinterpret_cast<const bf16x8*>(A + (size_t)ra1 * K + kf * 32 + acol);
    }
#pragma unroll
    for (int nf = 0; nf < 8; nf++) {
      bf16x8 b = *reinterpret_cast<const bf16x8*>(
          &Blds[((nf * nkf + kf) * 64 + lane) * 8]);
      acc[0][nf] = __builtin_amdgcn_mfma_f32_16x16x32_bf16(a0, b, acc[0][nf], 0, 0, 0);
      acc[1][nf] = __builtin_amdgcn_mfma_f32_16x16x32_bf16(a1, b, acc[1][nf], 0, 0, 0);
    }
  }

#pragma unroll
  for (int m = 0; m < 2; m++) {
    int row0 = rbase + m * 16 + (lane >> 4) * 4;
#pragma unroll
    for (int nf = 0; nf < 8; nf++) {
      int col = nf * 16 + (lane & 15);
      float bv = bias[col];
#pragma unroll
      for (int r = 0; r < 4; r++) {
        int row = row0 + r;
        if (row < M) {
          float v = acc[m][nf][r] + bv;
          if (RELU) v = fmaxf(v, 0.f);
          C[(size_t)row * 128 + col] = f2b(v);
        }
      }
    }
  }
}

// ---- conv aggregation: CSR gather (4-edge unroll, 2 acc chains, ushort src) -
__global__ __launch_bounds__(256) void gather_conv(
    const ushort* __restrict__ h, const ushort* __restrict__ e_src,
    const int* __restrict__ row_ptr, const float* __restrict__ dis,
    const float* __restrict__ bias, ushort* __restrict__ y,
    float* __restrict__ partial) {
  __shared__ float red[2048];
  int tid = threadIdx.x;
  int gid = blockIdx.x * 256 + tid;
  int v = gid >> 4;  // grid == NB*16 exactly
  int c8 = gid & 15;
  const uint4* h4 = reinterpret_cast<const uint4*>(h);
  float sv = dis[v];
  float ss = sv * sv;
  uint4 hv = h4[(size_t)v * 16 + c8];
  float acc[8], acc2[8];
  acc[0] = bias[c8 * 8 + 0] + blo(hv.x) * ss;
  acc[1] = bias[c8 * 8 + 1] + bhi(hv.x) * ss;
  acc[2] = bias[c8 * 8 + 2] + blo(hv.y) * ss;
  acc[3] = bias[c8 * 8 + 3] + bhi(hv.y) * ss;
  acc[4] = bias[c8 * 8 + 4] + blo(hv.z) * ss;
  acc[5] = bias[c8 * 8 + 5] + bhi(hv.z) * ss;
  acc[6] = bias[c8 * 8 + 6] + blo(hv.w) * ss;
  acc[7] = bias[c8 * 8 + 7] + bhi(hv.w) * ss;
#pragma unroll
  for (int j = 0; j < 8; j++) acc2[j] = 0.f;
  int beg = row_ptr[v], end = row_ptr[v + 1];
  int e = beg;
  for (; e + 4 <= end; e += 4) {
    int s0 = e_src[e], s1 = e_src[e + 1], s2 = e_src[e + 2], s3 = e_src[e + 3];
    uint4 q0 = h4[(size_t)s0 * 16 + c8];
    uint4 q1 = h4[(size_t)s1 * 16 + c8];
    uint4 q2 = h4[(size_t)s2 * 16 + c8];
    uint4 q3 = h4[(size_t)s3 * 16 + c8];
    float w0 = dis[s0] * sv, w1 = dis[s1] * sv;
    float w2 = dis[s2] * sv, w3 = dis[s3] * sv;
    acc[0] += blo(q0.x) * w0; acc2[0] += blo(q1.x) * w1;
    acc[1] += bhi(q0.x) * w0; acc2[1] += bhi(q1.x) * w1;
    acc[2] += blo(q0.y) * w0; acc2[2] += blo(q1.y) * w1;
    acc[3] += bhi(q0.y) * w0; acc2[3] += bhi(q1.y) * w1;
    acc[4] += blo(q0.z) * w0; acc2[4] += blo(q1.z) * w1;
    acc[5] += bhi(q0.z) * w0; acc2[5] += bhi(q1.z) * w1;
    acc[6] += blo(q0.w) * w0; acc2[6] += blo(q1.w) * w1;
    acc[7] += bhi(q0.w) * w0; acc2[7] += bhi(q1.w) * w1;
    acc[0] += blo(q2.x) * w2; acc2[0] += blo(q3.x) * w3;
    acc[1] += bhi(q2.x) * w2; acc2[1] += bhi(q3.x) * w3;
    acc[2] += blo(q2.y) * w2; acc2[2] += blo(q3.y) * w3;
    acc[3] += bhi(q2.y) * w2; acc2[3] += bhi(q3.y) * w3;
    acc[4] += blo(q2.z) * w2; acc2[4] += blo(q3.z) * w3;
    acc[5] += bhi(q2.z) * w2; acc2[5] += bhi(q3.z) * w3;
    acc[6] += blo(q2.w) * w2; acc2[6] += blo(q3.w) * w3;
    acc[7] += bhi(q2.w) * w2; acc2[7] += bhi(q3.w) * w3;
  }
  for (; e < end; ++e) {
    int s0 = e_src[e];
    uint4 q0 = h4[(size_t)s0 * 16 + c8];
    float w0 = dis[s0] * sv;
    acc[0] += blo(q0.x) * w0; acc[1] += bhi(q0.x) * w0;
    acc[2] += blo(q0.y) * w0; acc[3] += bhi(q0.y) * w0;
    acc[4] += blo(q0.z) * w0; acc[5] += bhi(q0.z) * w0;
    acc[6] += blo(q0.w) * w0; acc[7] += bhi(q0.w) * w0;
  }
#pragma unroll
  for (int j = 0; j < 8; j++) acc[j] = fmaxf(acc[j] + acc2[j], 0.f);
  uint4 o;
  o.x = (uint)f2b(acc[0]) | ((uint)f2b(acc[1]) << 16);
  o.y = (uint)f2b(acc[2]) | ((uint)f2b(acc[3]) << 16);
  o.z = (uint)f2b(acc[4]) | ((uint)f2b(acc[5]) << 16);
  o.w = (uint)f2b(acc[6]) | ((uint)f2b(acc[7]) << 16);
  reinterpret_cast<uint4*>(y)[(size_t)v * 16 + c8] = o;

  // fused per-block stats partials (no atomics)
#pragma unroll
  for (int j = 0; j < 8; j++) red[tid * 8 + j] = acc[j];
  __syncthreads();
  for (int st = 128; st >= 16; st >>= 1) {
    if (tid < st)
#pragma unroll
      for (int j = 0; j < 8; j++) red[tid * 8 + j] += red[(tid + st) * 8 + j];
    __syncthreads();
  }
  if (tid < 16)
#pragma unroll
    for (int j = 0; j < 8; j++)
      partial[(size_t)blockIdx.x * 256 + tid * 8 + j] = red[tid * 8 + j];
  __syncthreads();
#pragma unroll
  for (int j = 0; j < 8; j++) red[tid * 8 + j] = acc[j] * acc[j];
  __syncthreads();
  for (int st = 128; st >= 16; st >>= 1) {
    if (tid < st)
#pragma unroll
      for (int j = 0; j < 8; j++) red[tid * 8 + j] += red[(tid + st) * 8 + j];
    __syncthreads();
  }
  if (tid < 16)
#pragma unroll
    for (int j = 0; j < 8; j++)
      partial[(size_t)blockIdx.x * 256 + 128 + tid * 8 + j] = red[tid * 8 + j];
}

// ---- pooling: vectorized segmented gather (16 lanes/graph, uint4) ----------
__global__ __launch_bounds__(256) void pool_gather(const ushort* __restrict__ emb,
                                                   const int* __restrict__ g_start,
                                                   float* __restrict__ g) {
  int gid = blockIdx.x * 256 + threadIdx.x;
  int gr = gid >> 4;
  if (gr >= NG) return;
  int c8 = gid & 15;
  const uint4* e4 = reinterpret_cast<const uint4*>(emb);
  float acc[8];
#pragma unroll
  for (int j = 0; j < 8; j++) acc[j] = 0.f;
  int beg = g_start[gr], end = g_start[gr + 1];
  for (int v = beg; v < end; ++v) {
    uint4 q = e4[(size_t)v * 16 + c8];
    acc[0] += blo(q.x); acc[1] += bhi(q.x);
    acc[2] += blo(q.y); acc[3] += bhi(q.y);
    acc[4] += blo(q.z); acc[5] += bhi(q.z);
    acc[6] += blo(q.w); acc[7] += bhi(q.w);
  }
  float4* gp = reinterpret_cast<float4*>(g + (size_t)gr * 128 + c8 * 8);
  gp[0] = make_float4(acc[0], acc[1], acc[2], acc[3]);
  gp[1] = make_float4(acc[4], acc[5], acc[6], acc[7]);
}

// ---- head: 128->64->32->2 MLP, 4 graphs/block (500 blocks), LDS weights ----
__global__ __launch_bounds__(128) void head_kernel(
    const float* __restrict__ g, const float* __restrict__ w1,
    const float* __restrict__ b1, const float* __restrict__ w2,
    const float* __restrict__ b2, const float* __restrict__ wp,
    const float* __restrict__ bp, float* __restrict__ out) {
  __shared__ float w1s[128 * 64];
  __shared__ float w2s[64 * 32];
  __shared__ float wps[64];
  __shared__ float sg[128], ph[128], sh1[64], sh2[32];
  int tid = threadIdx.x;
  for (int i = tid; i < 2048; i += 128)
    reinterpret_cast<float4*>(w1s)[i] = reinterpret_cast<const float4*>(w1)[i];
  for (int i = tid; i < 512; i += 128)
    reinterpret_cast<float4*>(w2s)[i] = reinterpret_cast<const float4*>(w2)[i];
  if (tid < 64) wps[tid] = wp[tid];
  __syncthreads();

  for (int gi = 0; gi < 4; gi++) {
    int gid = blockIdx.x * 4 + gi;
    if (gid >= NG) break;
    sg[tid] = g[(size_t)gid * 128 + tid];
    __syncthreads();
    {
      int o = tid & 63, h = tid >> 6;
      float acc = 0.f;
#pragma unroll 8
      for (int k = 0; k < 64; k++)
        acc += sg[h * 64 + k] * w1s[(h * 64 + k) * 64 + o];
      ph[tid] = acc;
    }
    __syncthreads();
    if (tid < 64) sh1[tid] = fmaxf(b1[tid] + ph[tid] + ph[tid + 64], 0.f);
    __syncthreads();
    {
      int o = tid & 31, q = tid >> 5;
      float acc = 0.f;
#pragma unroll 8
      for (int k = 0; k < 16; k++)
        acc += sh1[q * 16 + k] * w2s[(q * 16 + k) * 32 + o];
      ph[tid] = acc;
    }
    __syncthreads();
    if (tid < 32)
      sh2[tid] = fmaxf(
          b2[tid] + ph[tid] + ph[tid + 32] + ph[tid + 64] + ph[tid + 96], 0.f);
    __syncthreads();
    if (tid < 2) {
      float acc = bp[tid];
#pragma unroll
      for (int k = 0; k < 32; k++) acc += sh2[k] * wps[k * 2 + tid];
      out[(size_t)gid * 2 + tid] = acc;
    }
    __syncthreads();
  }
}

extern "C" void kernel_launch(void* const* d_in, const int* in_sizes, int n_in,
                              void* d_out, int out_size, void* d_ws,
                              size_t ws_size, hipStream_t stream) {
  const float* x = (const float*)d_in[0];
  const int* ei = (const int*)d_in[1];
  const int* batch = (const int*)d_in[2];
  const float* lin_w = (const float*)d_in[3];
  const float* lin_b = (const float*)d_in[4];
  const float* conv_w = (const float*)d_in[5];
  const float* conv_b = (const float*)d_in[6];
  const float* bn_g = (const float*)d_in[7];
  const float* bn_b = (const float*)d_in[8];
  const float* emb_w = (const float*)d_in[9];
  const float* emb_b = (const float*)d_in[10];
  const float* m1w = (const float*)d_in[11];
  const float* m1b = (const float*)d_in[12];
  const float* m2w = (const float*)d_in[13];
  const float* m2b = (const float*)d_in[14];
  const float* pw = (const float*)d_in[15];
  const float* pb = (const float*)d_in[16];
  float* out = (float*)d_out;

  ushort* buf0 = (ushort*)d_ws;                  // [MPAD,128] bf16
  ushort* buf1 = buf0 + (size_t)MPAD * 128;      // [MPAD,128] bf16
  ushort* Bp = buf1 + (size_t)MPAD * 128;        // 5 * 16384 packed weights
  float* fbase = (float*)(Bp + 5 * 16384);
  float* dis = fbase;                            // [NB] pad 50048
  float* partial = dis + 50048;                  // [3125*256]
  float* partial2 = partial + (size_t)GATHER_BLKS * 256;  // [125*256]
  float* biasb = partial2 + RED_L1_BLKS * 256;   // [5*128]
  float* g = biasb + 640;                        // [NG*128]
  int* cnt = (int*)(g + (size_t)NG * 128);       // [NB]
  int* row_ptr = cnt + NB;                       // [NB+1] pad 50008
  ushort* rank = (ushort*)(row_ptr + 50008);     // [NE] ushort
  ushort* e_src = rank + NE;                     // [NE] ushort
  int* bsum = (int*)(e_src + NE);                // [256]
  int* g_start = bsum + 256;                     // [NG+1]

  const int* src = ei;
  const int* dst = ei + NE;

  ushort* Bp0 = Bp;              // lin (K=64)
  ushort* Bp1 = Bp + 16384;      // conv0
  ushort* Bp2 = Bp + 2 * 16384;  // conv1 (BN0 folded)
  ushort* Bp3 = Bp + 3 * 16384;  // conv2 (BN1 folded)
  ushort* Bp4 = Bp + 4 * 16384;  // emb   (BN2 folded)
  float* bias0 = biasb;
  float* bias1 = biasb + 128;
  float* bias2 = biasb + 256;
  float* bias3 = biasb + 384;
  float* bias4 = biasb + 512;

  pack_init<<<220, 256, 0, stream>>>(lin_w, lin_b, conv_w, Bp0, Bp1, bias0,
                                     bias1, cnt);
  rank_kernel<<<EBLK, 256, 0, stream>>>(dst, cnt, rank);
  scan1<<<NBLK, 256, 0, stream>>>(cnt, row_ptr, bsum, dis);
  scan3<<<NBLK, 256, 0, stream>>>(row_ptr, bsum);
  fill2<<<EBLK + 8, 256, 0, stream>>>(src, dst, rank, row_ptr, e_src, batch,
                                      g_start);

  const int GB = (NB + 127) / 128;

  // linatoms (f32 A converted inline)
  gemm_mfma<false, true><<<GB, 256, 0, stream>>>(x, Bp0, bias0, buf0, NB, 64);

  // layer 0
  gemm_mfma<false, false><<<GB, 256, 0, stream>>>(buf0, Bp1, bias1, buf1, NB, 128);
  gather_conv<<<GATHER_BLKS, 256, 0, stream>>>(buf1, e_src, row_ptr, dis,
                                               conv_b, buf0, partial);
  reduce_l1<<<RED_L1_BLKS, 256, 0, stream>>>(partial, partial2);
  pack_final<<<16, 256, 0, stream>>>(conv_w + 16384, partial2, bn_g, bn_b,
                                     nullptr, Bp2, bias2);
  // layer 1
  gemm_mfma<false, false><<<GB, 256, 0, stream>>>(buf0, Bp2, bias2, buf1, NB, 128);
  gather_conv<<<GATHER_BLKS, 256, 0, stream>>>(buf1, e_src, row_ptr, dis,
                                               conv_b + 128, buf0, partial);
  reduce_l1<<<RED_L1_BLKS, 256, 0, stream>>>(partial, partial2);
  pack_final<<<16, 256, 0, stream>>>(conv_w + 2 * 16384, partial2, bn_g + 128,
                                     bn_b + 128, nullptr, Bp3, bias3);
  // layer 2
  gemm_mfma<false, false><<<GB, 256, 0, stream>>>(buf0, Bp3, bias3, buf1, NB, 128);
  gather_conv<<<GATHER_BLKS, 256, 0, stream>>>(buf1, e_src, row_ptr, dis,
                                               conv_b + 256, buf0, partial);
  reduce_l1<<<RED_L1_BLKS, 256, 0, stream>>>(partial, partial2);
  pack_final<<<16, 256, 0, stream>>>(emb_w, partial2, bn_g + 256, bn_b + 256,
                                     emb_b, Bp4, bias4);
  // emb + pool + head
  gemm_mfma<true, false><<<GB, 256, 0, stream>>>(buf0, Bp4, bias4, buf1, NB, 128);
  pool_gather<<<(NG * 16 + 255) / 256, 256, 0, stream>>>(buf1, g_start, g);
  head_kernel<<<(NG + 3) / 4, 128, 0, stream>>>(g, m1w, m1b, m2w, m2b, pw, pb,
                                                out);
}